// Round 13
// baseline (384.291 us; speedup 1.0000x reference)
//
#include <hip/hip_runtime.h>

// AdaptiveGraph on MI355X — v13: R12 (346us, best) + XCD-local atomic accumulation.
// Mechanism: outp receives 8.4M fp32 atomicAdds; each (row,h) line gets adds from the
// 8 cs-sibling blocks of one row-block. Old decomposition (rb=bid>>3, cs=bid&7) put
// those 8 siblings on 8 DIFFERENT XCDs (dispatch round-robins bid%8 over XCDs) ->
// every add migrates the line across the fabric. New decomposition (rb=bid&127,
// cs=bid>>7) gives all siblings wgid%8 = rb%8 -> SAME XCD -> atomics resolve in one
// local L2. Zb/ZbT (2MB each) stay L2-resident per XCD either way. Same flip in
// k_rowsum. Everything else byte-identical to R12.

#define NR 8192
#define KD 256
#define HD 128

typedef short v8s __attribute__((ext_vector_type(8)));
typedef float v4f __attribute__((ext_vector_type(4)));
typedef float v2f __attribute__((ext_vector_type(2)));

static __device__ __forceinline__ ushort f2bf(float f) {
    union { float f; unsigned u; } c; c.f = f;
    unsigned u = c.u;
    u += 0x7fffu + ((u >> 16) & 1u);  // RNE; inputs finite
    return (ushort)(u >> 16);
}
static __device__ __forceinline__ float bf2f(ushort b) {
    union { unsigned u; float f; } c; c.u = ((unsigned)b) << 16; return c.f;
}
static __device__ __forceinline__ unsigned pk2(float a, float b) {
    union { float f; unsigned u; } x, y; x.f = a; y.f = b;
    unsigned ua = x.u + 0x7fffu + ((x.u >> 16) & 1u);
    unsigned ub = y.u + 0x7fffu + ((y.u >> 16) & 1u);
    return (ua >> 16) | (ub & 0xffff0000u);
}

// LDS-visibility barrier: wait own ds ops, then block-barrier. No vmcnt drain.
static __device__ __forceinline__ void lds_barrier() {
    asm volatile("s_waitcnt lgkmcnt(0)" ::: "memory");
    __builtin_amdgcn_s_barrier();
}

// ---------------- K1: Z = X @ W^T (MFMA, hi/lo bf16 split) — R12 verbatim ----------------
__global__ __launch_bounds__(256) void k_z(const float* __restrict__ X,
                                           const float* __restrict__ W,
                                           ushort* __restrict__ Zb,
                                           ushort* __restrict__ ZbT) {
    __shared__ ushort Xhi[16][264];
    __shared__ ushort Xlo[16][264];
    int tid = threadIdx.x, lane = tid & 63, wave = tid >> 6;
    int lm = lane & 15, lq = lane >> 4;
    int n0 = blockIdx.x * 16;
    int hbase = wave * 32;
    v8s Whi[2][8], Wlo[2][8];
#pragma unroll
    for (int hi = 0; hi < 2; ++hi) {
        const float* wp = W + (hbase + hi * 16 + lm) * KD + lq * 8;
#pragma unroll
        for (int ks = 0; ks < 8; ++ks) {
            float4 w0 = *(const float4*)(wp + ks * 32);
            float4 w1 = *(const float4*)(wp + ks * 32 + 4);
            float wv[8] = {w0.x, w0.y, w0.z, w0.w, w1.x, w1.y, w1.z, w1.w};
#pragma unroll
            for (int j = 0; j < 8; ++j) {
                ushort h = f2bf(wv[j]);
                Whi[hi][ks][j] = (short)h;
                Wlo[hi][ks][j] = (short)f2bf(wv[j] - bf2f(h));
            }
        }
    }
#pragma unroll
    for (int t = 0; t < 4; ++t) {
        int idx = tid + t * 256;
        int r = idx >> 6, c4 = (idx & 63) * 4;
        float4 x = *(const float4*)(X + (size_t)(n0 + r) * KD + c4);
        ushort h0 = f2bf(x.x), h1 = f2bf(x.y), h2 = f2bf(x.z), h3 = f2bf(x.w);
        unsigned a = ((unsigned)h0) | ((unsigned)h1 << 16);
        unsigned b = ((unsigned)h2) | ((unsigned)h3 << 16);
        unsigned c = ((unsigned)f2bf(x.x - bf2f(h0))) | ((unsigned)f2bf(x.y - bf2f(h1)) << 16);
        unsigned d = ((unsigned)f2bf(x.z - bf2f(h2))) | ((unsigned)f2bf(x.w - bf2f(h3)) << 16);
        *(uint2*)&Xhi[r][c4] = make_uint2(a, b);
        *(uint2*)&Xlo[r][c4] = make_uint2(c, d);
    }
    __syncthreads();
    {
        v8s Ah[8], Al[8];
#pragma unroll
        for (int ks = 0; ks < 8; ++ks) {
            Ah[ks] = *(const v8s*)&Xhi[lm][ks * 32 + lq * 8];
            Al[ks] = *(const v8s*)&Xlo[lm][ks * 32 + lq * 8];
        }
        v4f acc[2] = {{0.f, 0.f, 0.f, 0.f}, {0.f, 0.f, 0.f, 0.f}};
#pragma unroll
        for (int ks = 0; ks < 8; ++ks)
#pragma unroll
            for (int hi = 0; hi < 2; ++hi) {
                acc[hi] = __builtin_amdgcn_mfma_f32_16x16x32_bf16(Ah[ks], Whi[hi][ks], acc[hi], 0, 0, 0);
                acc[hi] = __builtin_amdgcn_mfma_f32_16x16x32_bf16(Ah[ks], Wlo[hi][ks], acc[hi], 0, 0, 0);
                acc[hi] = __builtin_amdgcn_mfma_f32_16x16x32_bf16(Al[ks], Whi[hi][ks], acc[hi], 0, 0, 0);
            }
#pragma unroll
        for (int hi = 0; hi < 2; ++hi) {
            int h = hbase + hi * 16 + lm;
            int nb = n0 + lq * 4;
            ushort b0 = f2bf(acc[hi][0]), b1 = f2bf(acc[hi][1]);
            ushort b2 = f2bf(acc[hi][2]), b3 = f2bf(acc[hi][3]);
            Zb[(size_t)(nb + 0) * HD + h] = b0;
            Zb[(size_t)(nb + 1) * HD + h] = b1;
            Zb[(size_t)(nb + 2) * HD + h] = b2;
            Zb[(size_t)(nb + 3) * HD + h] = b3;
            *(uint2*)&ZbT[(size_t)h * NR + nb] =
                make_uint2(((unsigned)b0) | ((unsigned)b1 << 16), ((unsigned)b2) | ((unsigned)b3 << 16));
        }
    }
}

// ---------------- K2: rowsum — R12 loop, XCD-local decomposition ----------------
// grid 1024 = 16 cs x 64 rb (rb = bid&63 -> all cs-siblings of a row-block on one XCD).
__global__ __launch_bounds__(256) void k_rowsum(const ushort* __restrict__ Zb,
                                                float* __restrict__ rowsum) {
    __shared__ ushort ZC[2][64][136];
    int tid = threadIdx.x, lane = tid & 63, wave = tid >> 6;
    int lm = lane & 15, lq = lane >> 4;
    int rb = blockIdx.x & 63, cs = blockIdx.x >> 6;
    int row0 = rb * 128, cstart = cs * 512;
    v8s Bfr[2][4];
#pragma unroll
    for (int ri = 0; ri < 2; ++ri)
#pragma unroll
        for (int ks = 0; ks < 4; ++ks)
            Bfr[ri][ks] =
                *(const v8s*)(Zb + (size_t)(row0 + wave * 32 + ri * 16 + lm) * HD + ks * 32 + lq * 8);
    float rs[2] = {0.f, 0.f};
#pragma unroll
    for (int t = 0; t < 4; ++t) {
        int idx = tid + t * 256;
        int r = idx >> 4, c8 = (idx & 15) * 8;
        *(uint4*)&ZC[0][r][c8] = *(const uint4*)(Zb + (size_t)(cstart + r) * HD + c8);
    }
    __syncthreads();
    for (int it = 0; it < 8; ++it) {
        int cur = it & 1;
        int c0 = cstart + it * 64;
        uint4 sr[4];
        if (it < 7) {
#pragma unroll
            for (int t = 0; t < 4; ++t) {
                int idx = tid + t * 256;
                int r = idx >> 4, c8 = (idx & 15) * 8;
                sr[t] = *(const uint4*)(Zb + (size_t)(c0 + 64 + r) * HD + c8);
            }
        }
#pragma unroll
        for (int ci = 0; ci < 4; ++ci) {
            v8s Af[4];
#pragma unroll
            for (int ks = 0; ks < 4; ++ks)
                Af[ks] = *(const v8s*)&ZC[cur][ci * 16 + lm][ks * 32 + lq * 8];
            v4f a0 = {0.f, 0.f, 0.f, 0.f}, a1 = {0.f, 0.f, 0.f, 0.f};
#pragma unroll
            for (int ks = 0; ks < 4; ++ks) {
                a0 = __builtin_amdgcn_mfma_f32_16x16x32_bf16(Af[ks], Bfr[0][ks], a0, 0, 0, 0);
                a1 = __builtin_amdgcn_mfma_f32_16x16x32_bf16(Af[ks], Bfr[1][ks], a1, 0, 0, 0);
            }
            rs[0] += fmaxf(a0[0], 0.f) + fmaxf(a0[1], 0.f) + fmaxf(a0[2], 0.f) + fmaxf(a0[3], 0.f);
            rs[1] += fmaxf(a1[0], 0.f) + fmaxf(a1[1], 0.f) + fmaxf(a1[2], 0.f) + fmaxf(a1[3], 0.f);
        }
        if (it < 7) {
#pragma unroll
            for (int t = 0; t < 4; ++t) {
                int idx = tid + t * 256;
                int r = idx >> 4, c8 = (idx & 15) * 8;
                *(uint4*)&ZC[cur ^ 1][r][c8] = sr[t];
            }
        }
        __syncthreads();
    }
#pragma unroll
    for (int ri = 0; ri < 2; ++ri) {
        float v = rs[ri];
        v += __shfl_xor(v, 16, 64);
        v += __shfl_xor(v, 32, 64);
        if (lq == 0) atomicAdd(&rowsum[row0 + wave * 32 + ri * 16 + lm], v);
    }
}

// ---------------- K3: A write + out accumulate — XCD-local decomposition ----------------
// grid 1024 = 8 cs x 128 rb (rb = bid&127 -> all 8 cs-siblings of a row-block share an
// XCD -> outp atomics resolve in one local L2). LDS 52KB -> 3 blocks/CU.
__global__ __launch_bounds__(256) void k_main(const ushort* __restrict__ Zb,
                                              const ushort* __restrict__ ZbT,
                                              const float* __restrict__ rowsum,
                                              float* __restrict__ outp,
                                              float* __restrict__ Ap) {
    __shared__ ushort ZC[2][64][136];
    __shared__ ushort PT[2][64][72];
    int tid = threadIdx.x, lane = tid & 63, wave = tid >> 6;
    int lm = lane & 15, lq = lane >> 4;
    int rb = blockIdx.x & 127, cs = blockIdx.x >> 7;
    int row0 = rb * 64, colb = cs * 1024;
    int wr2 = wave >> 1, wc2 = wave & 1;
    v8s Bfr[2][4];  // one-time reg B-frags (rows of this strip), S-phase
#pragma unroll
    for (int ri = 0; ri < 2; ++ri)
#pragma unroll
        for (int ks = 0; ks < 4; ++ks)
            Bfr[ri][ks] =
                *(const v8s*)(Zb + (size_t)(row0 + wr2 * 32 + ri * 16 + lm) * HD + ks * 32 + lq * 8);
    float rsv[2];
#pragma unroll
    for (int ri = 0; ri < 2; ++ri)
        rsv[ri] = 1.0f / (rowsum[row0 + wr2 * 32 + ri * 16 + lm] + 1e-6f);
    // U accumulators: wave owns h-quarter [wave*32, wave*32+32), all 64 rows
    v4f U[4][2];
#pragma unroll
    for (int rA = 0; rA < 4; ++rA)
#pragma unroll
        for (int hi = 0; hi < 2; ++hi) U[rA][hi] = (v4f){0.f, 0.f, 0.f, 0.f};

    // prologue: stage ZC[0]
#pragma unroll
    for (int t = 0; t < 4; ++t) {
        int idx = tid + t * 256;
        int r = idx >> 4, c8 = (idx & 15) * 8;
        *(uint4*)&ZC[0][r][c8] = *(const uint4*)(Zb + (size_t)(colb + r) * HD + c8);
    }
    __syncthreads();

    int l5 = lane >> 5;         // A-store: row parity
    int c2 = (lane & 31) * 2;   // A-store: col pair

    for (int it = 0; it < 16; ++it) {
        int cur = it & 1;
        int c0 = colb + it * 64;
        uint4 sr[4];
        if (it < 15) {
#pragma unroll
            for (int t = 0; t < 4; ++t) {
                int idx = tid + t * 256;
                int r = idx >> 4, c8 = (idx & 15) * 8;
                sr[t] = *(const uint4*)(Zb + (size_t)(c0 + 64 + r) * HD + c8);
            }
        }
        // U-phase B-operand: wave's own 32-h quarter -> 4 loads, no intra-block duplication
        v8s Bz[2][2];
#pragma unroll
        for (int hi = 0; hi < 2; ++hi)
#pragma unroll
            for (int ks = 0; ks < 2; ++ks)
                Bz[hi][ks] = *(const v8s*)(ZbT + (size_t)(wave * 32 + hi * 16 + lm) * NR + c0 +
                                           ks * 32 + lq * 8);
        // S phase: S^T = (ZC as A) x (Bfr as B); D: r=lm, c=lq*4+reg (unchanged math)
#pragma unroll
        for (int ci = 0; ci < 2; ++ci) {
            v8s Af[4];
#pragma unroll
            for (int ks = 0; ks < 4; ++ks)
                Af[ks] = *(const v8s*)&ZC[cur][wc2 * 32 + ci * 16 + lm][ks * 32 + lq * 8];
            v4f S0 = {0.f, 0.f, 0.f, 0.f}, S1 = {0.f, 0.f, 0.f, 0.f};
#pragma unroll
            for (int ks = 0; ks < 4; ++ks) {
                S0 = __builtin_amdgcn_mfma_f32_16x16x32_bf16(Af[ks], Bfr[0][ks], S0, 0, 0, 0);
                S1 = __builtin_amdgcn_mfma_f32_16x16x32_bf16(Af[ks], Bfr[1][ks], S1, 0, 0, 0);
            }
            int cb = wc2 * 32 + ci * 16 + lq * 4;
            {
                float f0 = fmaxf(S0[0], 0.f) * rsv[0], f1 = fmaxf(S0[1], 0.f) * rsv[0];
                float f2 = fmaxf(S0[2], 0.f) * rsv[0], f3 = fmaxf(S0[3], 0.f) * rsv[0];
                *(uint2*)&PT[cur][wr2 * 32 + lm][cb] = make_uint2(pk2(f0, f1), pk2(f2, f3));
            }
            {
                float f0 = fmaxf(S1[0], 0.f) * rsv[1], f1 = fmaxf(S1[1], 0.f) * rsv[1];
                float f2 = fmaxf(S1[2], 0.f) * rsv[1], f3 = fmaxf(S1[3], 0.f) * rsv[1];
                *(uint2*)&PT[cur][wr2 * 32 + 16 + lm][cb] = make_uint2(pk2(f0, f1), pk2(f2, f3));
            }
        }
        if (it < 15) {
#pragma unroll
            for (int t = 0; t < 4; ++t) {
                int idx = tid + t * 256;
                int r = idx >> 4, c8 = (idx & 15) * 8;
                *(uint4*)&ZC[cur ^ 1][r][c8] = sr[t];
            }
        }
        lds_barrier();  // PT[cur] + ZC[nxt] ready; Bz/nt-stores stay in flight
        // A-stores from PT (PT IS bf16(A)): coalesced — 2 x 256B segments per instr
#pragma unroll
        for (int rr = 0; rr < 8; ++rr) {
            int r = wave * 16 + rr * 2 + l5;
            unsigned pv = *(const unsigned*)&PT[cur][r][c2];
            v2f o;
            o.x = bf2f((ushort)(pv & 0xffffu));
            o.y = bf2f((ushort)(pv >> 16));
            __builtin_nontemporal_store(o, (v2f*)(Ap + (size_t)(row0 + r) * NR + c0 + c2));
        }
        // U phase: U[r][h] += P[r][c] * Z[c][h]; A = PT frags (all 64 rows), B = Bz regs
#pragma unroll
        for (int ks = 0; ks < 2; ++ks) {
            v8s Pf[4];
#pragma unroll
            for (int rA = 0; rA < 4; ++rA)
                Pf[rA] = *(const v8s*)&PT[cur][rA * 16 + lm][ks * 32 + lq * 8];
#pragma unroll
            for (int hi = 0; hi < 2; ++hi)
#pragma unroll
                for (int rA = 0; rA < 4; ++rA)
                    U[rA][hi] = __builtin_amdgcn_mfma_f32_16x16x32_bf16(Pf[rA], Bz[hi][ks], U[rA][hi], 0, 0, 0);
        }
    }
    // epilogue: D layout -> r = row0 + rA*16 + lq*4 + j, h = wave*32 + hi*16 + lm
#pragma unroll
    for (int rA = 0; rA < 4; ++rA)
#pragma unroll
        for (int hi = 0; hi < 2; ++hi)
#pragma unroll
            for (int j = 0; j < 4; ++j)
                atomicAdd(&outp[(size_t)(row0 + rA * 16 + lq * 4 + j) * HD +
                                wave * 32 + hi * 16 + lm],
                          U[rA][hi][j]);
}

extern "C" void kernel_launch(void* const* d_in, const int* in_sizes, int n_in,
                              void* d_out, int out_size, void* d_ws, size_t ws_size,
                              hipStream_t stream) {
    (void)in_sizes; (void)n_in; (void)out_size; (void)ws_size;
    const float* X = (const float*)d_in[0];
    const float* W = (const float*)d_in[1];
    float* outp = (float*)d_out;
    float* Ap = outp + (size_t)NR * HD;  // A follows out in d_out
    char* ws = (char*)d_ws;
    ushort* Zb = (ushort*)ws;                                 // 2 MB
    ushort* ZbT = (ushort*)(ws + (size_t)NR * HD * 2);        // 2 MB
    float* rowsum = (float*)(ws + (size_t)NR * HD * 4);       // 32 KB  (ws total 8.03MB, proven)

    (void)hipMemsetAsync(outp, 0, (size_t)NR * HD * sizeof(float), stream);
    (void)hipMemsetAsync(rowsum, 0, NR * sizeof(float), stream);
    k_z<<<dim3(NR / 16), dim3(256), 0, stream>>>(X, W, Zb, ZbT);
    k_rowsum<<<dim3(1024), dim3(256), 0, stream>>>(Zb, rowsum);
    k_main<<<dim3(1024), dim3(256), 0, stream>>>(Zb, ZbT, rowsum, outp, Ap);
}